// Round 16
// baseline (304.960 us; speedup 1.0000x reference)
//
#include <hip/hip_runtime.h>
#include <hip/hip_bf16.h>

// GAT 2-layer forward on MI355X. 7-kernel pipeline:
// prepW(+detect), fatA(gemm1 MFMA+logits ∥ edge-histogram), bsum(+prefix),
// bscan2, scatter, fillagg(deg+scan+fill + layer-1 aggregation + gemm2,
// bucket-local csr stays cache-hot), agg2.

#define F_IN 500
#define HEADS 8
#define HID 8
#define HD 64
#define CLS 3
#define NEG 0.2f
#define EPSV 1e-16f
#define LOG2E 1.44269504088896340736f

#define NBLK_H 256     // blocks in hist/scatter passes
#define NBKT_MAX 3136  // >= ceil(N/32)

typedef __attribute__((ext_vector_type(8))) short short8v;   // 8 bf16
typedef __attribute__((ext_vector_type(4))) float f32x4;

__device__ inline short bfs(float v) {
    __hip_bfloat16 b = __float2bfloat16(v);
    return *(short*)&b;
}

__device__ inline int ld_edge(const void* ei, long idx, int is64) {
    return is64 ? (int)((const long long*)ei)[idx] : ((const int*)ei)[idx];
}

// ---------- W1 -> bf16 slices (pre-swizzled) + edge dtype detect ----------
__global__ void k_prepW(const float* __restrict__ W1, ushort* __restrict__ W1b2,
                        const int* __restrict__ ei, int* __restrict__ flag) {
    if (blockIdx.x == 0 && threadIdx.x == 0) {
        int z = 0;
        for (int i = 1; i < 16; i += 2) z += (ei[i] == 0) ? 1 : 0;
        *flag = (z == 8) ? 1 : 0;
    }
    int i = blockIdx.x * 256 + threadIdx.x;
    if (i >= 16 * 64 * 32) return;
    int ks = i >> 11;
    int c = (i >> 5) & 63;
    int st = i & 31;
    int q = (st >> 3) ^ ((c >> 1) & 3);
    int k = ks * 32 + q * 8 + (st & 7);
    float v = (k < F_IN) ? W1[k * HD + c] : 0.f;
    __hip_bfloat16 b = __float2bfloat16(v);
    W1b2[i] = *(ushort*)&b;
}

// ---------- fatA: gemm1 (blocks < gB) || edge histogram (last NBLK_H) ----------
__device__ __forceinline__ void g1_stage(const float* __restrict__ x,
        const ushort* __restrict__ W1b2, char* smem, int buf, int ks,
        int rowb, int N, int lane, int w) {
    const int k0 = ks * 32;
    {
        const ushort* srcB = W1b2 + ks * 2048 + (w * 64 + lane) * 8;
        char* dstB = smem + 16384 + buf * 4096 + w * 1024;
        __builtin_amdgcn_global_load_lds(
            (const __attribute__((address_space(1))) void*)srcB,
            (__attribute__((address_space(3))) void*)dstB, 16, 0, 0);
    }
#pragma unroll
    for (int i = 0; i < 2; ++i) {
        int vt = i * 256 + w * 64 + lane;
        int row = vt >> 3;
        int c = (vt & 7) ^ (row & 7);
        int ke = k0 + c * 4; if (ke > 496) ke = 496;
        int rowg = rowb + row; if (rowg >= N) rowg = N - 1;
        const float* srcA = x + (long)rowg * F_IN + ke;
        char* dstA = smem + buf * 8192 + i * 4096 + w * 1024;
        __builtin_amdgcn_global_load_lds(
            (const __attribute__((address_space(1))) void*)srcA,
            (__attribute__((address_space(3))) void*)dstA, 16, 0, 0);
    }
}

__global__ __launch_bounds__(256) void k_fatA(const float* __restrict__ x,
        const ushort* __restrict__ W1b2,
        const float* __restrict__ asrc, const float* __restrict__ adst,
        float* __restrict__ als, float* __restrict__ ald,
        ushort* __restrict__ h1b, int N,
        const void* ei, int E, int nbkt, int* __restrict__ ghist,
        const int* __restrict__ flag) {
    __shared__ char smem[24576];
    int gB = (N + 63) >> 6;
    int t = threadIdx.x;

    if ((int)blockIdx.x >= gB) {
        // ================= histogram branch =================
        int hb = blockIdx.x - gB;
        int* h = (int*)smem;
        int tot = E + N;
        int epb = (tot + NBLK_H - 1) / NBLK_H;
        int e0 = hb * epb, e1 = min(tot, e0 + epb);
        for (int i = t; i < nbkt; i += 256) h[i] = 0;
        __syncthreads();
        int is64 = *flag;
        for (int e = e0 + t; e < e1; e += 256) {
            int dst = (e < E) ? ld_edge(ei, (long)E + e, is64) : (e - E);
            atomicAdd(&h[dst >> 5], 1);
        }
        __syncthreads();
        for (int i = t; i < nbkt; i += 256)
            ghist[hb * nbkt + i] = h[i];
        return;
    }

    // ================= gemm1 branch =================
    int lane = t & 63;
    int w = t >> 6;
    int l16 = lane & 15, oct = lane >> 4;
    int rowb = blockIdx.x * 64;

    f32x4 acc0 = {0.f, 0.f, 0.f, 0.f};
    f32x4 acc1 = {0.f, 0.f, 0.f, 0.f};
    f32x4 acc2 = {0.f, 0.f, 0.f, 0.f};
    f32x4 acc3 = {0.f, 0.f, 0.f, 0.f};

    g1_stage(x, W1b2, smem, 0, 0, rowb, N, lane, w);
    __syncthreads();

    int rl = w * 16 + l16;
    int asw = l16 & 7;
    int bsw = (l16 >> 1) & 3;

    for (int ks = 0; ks < 16; ++ks) {
        int cur = ks & 1;
        if (ks < 15)
            g1_stage(x, W1b2, smem, cur ^ 1, ks + 1, rowb, N, lane, w);
        const char* Ab = smem + cur * 8192;
        const char* Bb = smem + 16384 + cur * 4096;
        float4 x0 = *reinterpret_cast<const float4*>(
            Ab + rl * 128 + ((2 * oct + 0) ^ asw) * 16);
        float4 x1 = *reinterpret_cast<const float4*>(
            Ab + rl * 128 + ((2 * oct + 1) ^ asw) * 16);
        short8v a;
        a[0] = bfs(x0.x); a[1] = bfs(x0.y); a[2] = bfs(x0.z); a[3] = bfs(x0.w);
        a[4] = bfs(x1.x); a[5] = bfs(x1.y); a[6] = bfs(x1.z); a[7] = bfs(x1.w);
        short8v b0 = *reinterpret_cast<const short8v*>(
            Bb + (0 * 16 + l16) * 64 + (oct ^ bsw) * 16);
        short8v b1 = *reinterpret_cast<const short8v*>(
            Bb + (1 * 16 + l16) * 64 + (oct ^ bsw) * 16);
        short8v b2 = *reinterpret_cast<const short8v*>(
            Bb + (2 * 16 + l16) * 64 + (oct ^ bsw) * 16);
        short8v b3 = *reinterpret_cast<const short8v*>(
            Bb + (3 * 16 + l16) * 64 + (oct ^ bsw) * 16);
        acc0 = __builtin_amdgcn_mfma_f32_16x16x32_bf16(a, b0, acc0, 0, 0, 0);
        acc1 = __builtin_amdgcn_mfma_f32_16x16x32_bf16(a, b1, acc1, 0, 0, 0);
        acc2 = __builtin_amdgcn_mfma_f32_16x16x32_bf16(a, b2, acc2, 0, 0, 0);
        acc3 = __builtin_amdgcn_mfma_f32_16x16x32_bf16(a, b3, acc3, 0, 0, 0);
        __syncthreads();
    }

    float* fs = (float*)smem;   // 64 x 64 f32 = 16 KB
#pragma unroll
    for (int r = 0; r < 4; ++r) {
        int rl_ = w * 16 + oct * 4 + r;
        fs[rl_ * 64 + l16 +  0] = acc0[r];
        fs[rl_ * 64 + l16 + 16] = acc1[r];
        fs[rl_ * 64 + l16 + 32] = acc2[r];
        fs[rl_ * 64 + l16 + 48] = acc3[r];
    }
    __syncthreads();
#pragma unroll
    for (int j = t; j < 512; j += 256) {
        int row = j >> 3, h = j & 7;
        int gn = rowb + row;
        if (gn < N) {
            const float* hp = fs + row * 64 + h * 8;
            float4 v0 = *reinterpret_cast<const float4*>(hp);
            float4 v1 = *reinterpret_cast<const float4*>(hp + 4);
            const float* s = asrc + h * 8;
            const float* d = adst + h * 8;
            float s1 = v0.x * s[0] + v0.y * s[1] + v0.z * s[2] + v0.w * s[3]
                     + v1.x * s[4] + v1.y * s[5] + v1.z * s[6] + v1.w * s[7];
            float s2 = v0.x * d[0] + v0.y * d[1] + v0.z * d[2] + v0.w * d[3]
                     + v1.x * d[4] + v1.y * d[5] + v1.z * d[6] + v1.w * d[7];
            als[gn * 8 + h] = s1 * LOG2E;
            ald[gn * 8 + h] = s2 * LOG2E;
            ushort hb[8];
            hb[0] = (ushort)bfs(v0.x); hb[1] = (ushort)bfs(v0.y);
            hb[2] = (ushort)bfs(v0.z); hb[3] = (ushort)bfs(v0.w);
            hb[4] = (ushort)bfs(v1.x); hb[5] = (ushort)bfs(v1.y);
            hb[6] = (ushort)bfs(v1.z); hb[7] = (ushort)bfs(v1.w);
            *reinterpret_cast<uint4*>(h1b + (long)gn * HD + h * 8) =
                *reinterpret_cast<const uint4*>(hb);
        }
    }
}

// ================= CSR build tail =================

// bsum + bapply fused: per-block exclusive prefix into ghist in place.
__global__ void k_bsum(int* __restrict__ ghist, int* __restrict__ colsum, int nbkt) {
    int b = blockIdx.x * 256 + threadIdx.x;
    if (b >= nbkt) return;
    int run = 0;
    for (int i = 0; i < NBLK_H; i++) {
        int v = ghist[i * nbkt + b];
        ghist[i * nbkt + b] = run;
        run += v;
    }
    colsum[b] = run;
}

__global__ __launch_bounds__(256) void k_bscan2(const int* __restrict__ colsum,
        int* __restrict__ boff, int nbkt) {
    __shared__ int part[256];
    int per = (nbkt + 255) / 256;
    int t = threadIdx.x;
    int lo = t * per, hi = min(nbkt, lo + per);
    int s = 0;
    for (int i = lo; i < hi; i++) s += colsum[i];
    part[t] = s;
    __syncthreads();
    for (int off = 1; off < 256; off <<= 1) {
        int v = (t >= off) ? part[t - off] : 0;
        __syncthreads();
        part[t] += v;
        __syncthreads();
    }
    int run = (t > 0) ? part[t - 1] : 0;
    for (int i = lo; i < hi; i++) { boff[i] = run; run += colsum[i]; }
    if (t == 255) boff[nbkt] = part[255];
}

__global__ __launch_bounds__(256) void k_scatter(const void* ei, int E, int N, int nbkt,
        const int* __restrict__ ghist, const int* __restrict__ boff,
        uint* __restrict__ pairs, const int* flag) {
    __shared__ int cur[NBKT_MAX];
    int tot = E + N;
    int epb = (tot + NBLK_H - 1) / NBLK_H;
    int e0 = blockIdx.x * epb, e1 = min(tot, e0 + epb);
    for (int i = threadIdx.x; i < nbkt; i += 256)
        cur[i] = boff[i] + ghist[blockIdx.x * nbkt + i];
    __syncthreads();
    int is64 = *flag;
    for (int e = e0 + threadIdx.x; e < e1; e += 256) {
        int src, dst;
        if (e < E) { src = ld_edge(ei, e, is64); dst = ld_edge(ei, (long)E + e, is64); }
        else { src = dst = e - E; }
        int pos = atomicAdd(&cur[dst >> 5], 1);
        pairs[pos] = ((uint)src << 5) | (uint)(dst & 31);
    }
}

// ---------- fused fill + layer-1 aggregation + layer-2 projection ----------
// One block per 32-node bucket. Phase 1 = deg+scan+fill (csr written by this
// block stays L1/L2-hot). Phase 2 = agg1 for the same 32 nodes: 4 passes,
// each wave handles 2 nodes (32-lane halves, es=4 slots x h=8 heads).
__global__ __launch_bounds__(256) void k_fillagg(const uint* __restrict__ pairs,
        const int* __restrict__ boff, int* __restrict__ rowptr,
        int* __restrict__ csr, const ushort* __restrict__ h1b,
        const float* __restrict__ als, const float* __restrict__ ald,
        const float* __restrict__ b1, const float* __restrict__ W2,
        const float* __restrict__ as2, const float* __restrict__ ad2,
        float* __restrict__ h2p, float* __restrict__ ald2,
        int N, int nbkt) {
    __shared__ int cnt[32];
    __shared__ int sbase[32];
    __shared__ int cur[32];
    int b = blockIdx.x;
    int t = threadIdx.x;
    if (t < 32) { cnt[t] = 0; cur[t] = 0; }
    __syncthreads();
    int p0 = boff[b], p1 = boff[b + 1];
    for (int p = p0 + t; p < p1; p += 256)
        atomicAdd(&cnt[pairs[p] & 31], 1);
    __syncthreads();
    if (t < 32) {
        int pre = 0;
#pragma unroll
        for (int i = 0; i < 32; i++) pre += (i < t) ? cnt[i] : 0;
        sbase[t] = p0 + pre;
        int n = b * 32 + t;
        if (n < N) rowptr[n] = sbase[t];
    }
    if (b == 0 && t == 0) rowptr[N] = boff[nbkt];
    __syncthreads();
    for (int p = p0 + t; p < p1; p += 256) {
        uint v = pairs[p];
        int lo = v & 31;
        int pos = sbase[lo] + atomicAdd(&cur[lo], 1);
        csr[pos] = (int)(v >> 5);
    }
    __syncthreads();   // csr visible block-wide; LDS stable

    // ================= phase 2: aggregation =================
    int lane = t & 63;
    int wid = t >> 6;
    int half = lane >> 5;
    int es = (lane >> 3) & 3;
    int h = lane & 7;

#pragma unroll
    for (int pass = 0; pass < 4; ++pass) {
        int nib = pass * 8 + wid * 2 + half;
        int n = b * 32 + nib;
        bool act = (n < N);
        int nc = act ? n : (N - 1);
        int rs = sbase[nib];
        int re = rs + cnt[nib];
        float aldh = ald[nc * HEADS + h];

        float acc[4][8];
        float den[4] = {0.f, 0.f, 0.f, 0.f};
#pragma unroll
        for (int q = 0; q < 4; ++q)
#pragma unroll
            for (int j = 0; j < 8; ++j) acc[q][j] = 0.f;

        int jb = rs;
        for (; jb + 16 <= re; jb += 16) {
            int s[4]; float e[4]; float p[4]; uint4 u[4];
#pragma unroll
            for (int q = 0; q < 4; ++q) s[q] = csr[jb + q * 4 + es];
#pragma unroll
            for (int q = 0; q < 4; ++q) {
                e[q] = als[s[q] * HEADS + h] + aldh;
                u[q] = *reinterpret_cast<const uint4*>(h1b + (long)s[q] * HD + h * 8);
            }
#pragma unroll
            for (int q = 0; q < 4; ++q) {
                e[q] = fmaxf(e[q], NEG * e[q]);
                p[q] = exp2f(e[q]);
            }
#pragma unroll
            for (int q = 0; q < 4; ++q) {
                acc[q][0] += p[q] * __uint_as_float(u[q].x << 16);
                acc[q][1] += p[q] * __uint_as_float(u[q].x & 0xffff0000u);
                acc[q][2] += p[q] * __uint_as_float(u[q].y << 16);
                acc[q][3] += p[q] * __uint_as_float(u[q].y & 0xffff0000u);
                acc[q][4] += p[q] * __uint_as_float(u[q].z << 16);
                acc[q][5] += p[q] * __uint_as_float(u[q].z & 0xffff0000u);
                acc[q][6] += p[q] * __uint_as_float(u[q].w << 16);
                acc[q][7] += p[q] * __uint_as_float(u[q].w & 0xffff0000u);
                den[q] += p[q];
            }
        }
        for (; jb < re; jb += 4) {
            int eidx = jb + es;
            bool valid = (eidx < re);
            int s = csr[valid ? eidx : rs];
            float e = als[s * HEADS + h] + aldh;
            e = fmaxf(e, NEG * e);
            float p = valid ? exp2f(e) : 0.f;
            uint4 u = *reinterpret_cast<const uint4*>(h1b + (long)s * HD + h * 8);
            acc[0][0] += p * __uint_as_float(u.x << 16);
            acc[0][1] += p * __uint_as_float(u.x & 0xffff0000u);
            acc[0][2] += p * __uint_as_float(u.y << 16);
            acc[0][3] += p * __uint_as_float(u.y & 0xffff0000u);
            acc[0][4] += p * __uint_as_float(u.z << 16);
            acc[0][5] += p * __uint_as_float(u.z & 0xffff0000u);
            acc[0][6] += p * __uint_as_float(u.w << 16);
            acc[0][7] += p * __uint_as_float(u.w & 0xffff0000u);
            den[0] += p;
        }
        float a0 = (acc[0][0] + acc[1][0]) + (acc[2][0] + acc[3][0]);
        float a1 = (acc[0][1] + acc[1][1]) + (acc[2][1] + acc[3][1]);
        float a2 = (acc[0][2] + acc[1][2]) + (acc[2][2] + acc[3][2]);
        float a3 = (acc[0][3] + acc[1][3]) + (acc[2][3] + acc[3][3]);
        float a4 = (acc[0][4] + acc[1][4]) + (acc[2][4] + acc[3][4]);
        float a5 = (acc[0][5] + acc[1][5]) + (acc[2][5] + acc[3][5]);
        float a6 = (acc[0][6] + acc[1][6]) + (acc[2][6] + acc[3][6]);
        float a7 = (acc[0][7] + acc[1][7]) + (acc[2][7] + acc[3][7]);
        float dn = (den[0] + den[1]) + (den[2] + den[3]);
#pragma unroll
        for (int off = 8; off <= 16; off <<= 1) {
            dn += __shfl_xor(dn, off);
            a0 += __shfl_xor(a0, off); a1 += __shfl_xor(a1, off);
            a2 += __shfl_xor(a2, off); a3 += __shfl_xor(a3, off);
            a4 += __shfl_xor(a4, off); a5 += __shfl_xor(a5, off);
            a6 += __shfl_xor(a6, off); a7 += __shfl_xor(a7, off);
        }
        float sel_a = (es < 2) ? ((es == 0) ? a0 : a1) : ((es == 2) ? a2 : a3);
        float sel_b = (es < 2) ? ((es == 0) ? a4 : a5) : ((es == 2) ? a6 : a7);
        int da = h * 8 + es, db = da + 4;
        float inv = 1.f / (dn + EPSV);
        float oa = sel_a * inv + b1[da];
        float ob = sel_b * inv + b1[db];
        oa = (oa > 0.f) ? oa : __expf(oa) - 1.f;
        ob = (ob > 0.f) ? ob : __expf(ob) - 1.f;
        float p0 = oa * W2[da * CLS + 0] + ob * W2[db * CLS + 0];
        float p1 = oa * W2[da * CLS + 1] + ob * W2[db * CLS + 1];
        float p2 = oa * W2[da * CLS + 2] + ob * W2[db * CLS + 2];
#pragma unroll
        for (int off = 1; off <= 16; off <<= 1) {
            p0 += __shfl_xor(p0, off);
            p1 += __shfl_xor(p1, off);
            p2 += __shfl_xor(p2, off);
        }
        if ((lane & 31) == 0 && act) {
            float als2v = (p0 * as2[0] + p1 * as2[1] + p2 * as2[2]) * LOG2E;
            *reinterpret_cast<float4*>(h2p + (long)n * 4) =
                make_float4(p0, p1, p2, als2v);   // logit packed in .w
            ald2[n] = (p0 * ad2[0] + p1 * ad2[1] + p2 * ad2[2]) * LOG2E;
        }
    }
}

// ---------- Layer-2 pull aggregation: 2 nodes/wave, 1 line per edge ----------
__global__ __launch_bounds__(256) void k_agg2(const int* __restrict__ rowptr,
        const int* __restrict__ csr, const float* __restrict__ h2p,
        const float* __restrict__ ald2v,
        const float* __restrict__ b2, float* __restrict__ out, int N) {
    int n = blockIdx.x * 8 + (threadIdx.x >> 5);
    if (n >= N) return;
    int lane = threadIdx.x & 31;
    float aldv = ald2v[n];
    int rs = rowptr[n], re = rowptr[n + 1];
    float sum = 0.f, a0 = 0.f, a1 = 0.f, a2 = 0.f;
    for (int j = rs + lane; j < re; j += 32) {
        int s = csr[j];
        float4 hv = *reinterpret_cast<const float4*>(h2p + (long)s * 4);
        float e = hv.w + aldv;
        e = fmaxf(e, NEG * e);
        float p = exp2f(e);
        sum += p;
        a0 += p * hv.x;
        a1 += p * hv.y;
        a2 += p * hv.z;
    }
#pragma unroll
    for (int off = 1; off < 32; off <<= 1) {
        sum += __shfl_xor(sum, off);
        a0 += __shfl_xor(a0, off);
        a1 += __shfl_xor(a1, off);
        a2 += __shfl_xor(a2, off);
    }
    if (lane == 0) {
        float d = sum + EPSV;
        float v0 = a0 / d + b2[0], v1 = a1 / d + b2[1], v2 = a2 / d + b2[2];
        float mx = fmaxf(v0, fmaxf(v1, v2));
        float se = __expf(v0 - mx) + __expf(v1 - mx) + __expf(v2 - mx);
        float ls = mx + __logf(se);
        out[n * CLS + 0] = v0; out[n * CLS + 1] = v1; out[n * CLS + 2] = v2;
        long o2 = (long)N * CLS;
        out[o2 + n * CLS + 0] = v0 - ls;
        out[o2 + n * CLS + 1] = v1 - ls;
        out[o2 + n * CLS + 2] = v2 - ls;
    }
}

extern "C" void kernel_launch(void* const* d_in, const int* in_sizes, int n_in,
                              void* d_out, int out_size, void* d_ws, size_t ws_size,
                              hipStream_t stream) {
    const float* x   = (const float*)d_in[0];
    const void*  ei  = d_in[1];
    const float* W1  = (const float*)d_in[2];
    const float* as1 = (const float*)d_in[3];
    const float* ad1 = (const float*)d_in[4];
    const float* b1  = (const float*)d_in[5];
    const float* W2  = (const float*)d_in[6];
    const float* as2 = (const float*)d_in[7];
    const float* ad2 = (const float*)d_in[8];
    const float* b2  = (const float*)d_in[9];
    int N = in_sizes[0] / F_IN;
    int E = in_sizes[1] / 2;
    int tot = E + N;
    int nbkt = (N + 31) >> 5;

    char* w = (char*)d_ws;
    auto alloc = [&](size_t bytes) -> char* {
        char* p = w; w += (bytes + 255) & ~size_t(255); return p;
    };
    ushort* h1b    = (ushort*)alloc((size_t)N * HD * 2);
    float*  als1   = (float*)alloc((size_t)N * HEADS * 4);
    float*  ald1   = (float*)alloc((size_t)N * HEADS * 4);
    int*    rowptr = (int*)alloc((size_t)(N + 1) * 4);
    int*    csr    = (int*)alloc((size_t)tot * 4);
    float*  h2p    = (float*)alloc((size_t)N * 4 * 4);
    float*  ald2   = (float*)alloc((size_t)N * 4);
    ushort* W1b2   = (ushort*)alloc((size_t)16 * 64 * 32 * 2);
    int*    flag   = (int*)alloc(256);
    uint*   pairs  = (uint*)alloc((size_t)tot * 4);
    int*    ghist  = (int*)alloc((size_t)NBLK_H * nbkt * 4);
    int*    colsum = (int*)alloc((size_t)nbkt * 4);
    int*    boff   = (int*)alloc((size_t)(nbkt + 1) * 4);

    int gB = (N + 63) / 64;
    k_prepW<<<(16 * 64 * 32 + 255) / 256, 256, 0, stream>>>(W1, W1b2, (const int*)ei, flag);
    k_fatA<<<gB + NBLK_H, 256, 0, stream>>>(x, W1b2, as1, ad1, als1, ald1, h1b, N,
                                            ei, E, nbkt, ghist, flag);
    k_bsum<<<(nbkt + 255) / 256, 256, 0, stream>>>(ghist, colsum, nbkt);
    k_bscan2<<<1, 256, 0, stream>>>(colsum, boff, nbkt);
    k_scatter<<<NBLK_H, 256, 0, stream>>>(ei, E, N, nbkt, ghist, boff, pairs, flag);
    k_fillagg<<<nbkt, 256, 0, stream>>>(pairs, boff, rowptr, csr, h1b, als1, ald1,
                                        b1, W2, as2, ad2, h2p, ald2, N, nbkt);
    k_agg2<<<(N + 7) / 8, 256, 0, stream>>>(rowptr, csr, h2p, ald2, b2,
                                            (float*)d_out, N);
}

// Round 17
// 282.006 us; speedup vs baseline: 1.0814x; 1.0814x over previous
//
#include <hip/hip_runtime.h>
#include <hip/hip_bf16.h>

// GAT 2-layer forward on MI355X. 9-kernel pipeline (best-measured R13 config):
// prepW(+detect), fatA(gemm1 MFMA+logits ∥ edge-histogram), bsum, bscan2,
// bapply, scatter, fill3(deg+scan+fill), agg1(2 nodes/wave, +gemm2 fused),
// agg2 (1 line/edge via h2p.w logit packing).

#define F_IN 500
#define HEADS 8
#define HID 8
#define HD 64
#define CLS 3
#define NEG 0.2f
#define EPSV 1e-16f
#define LOG2E 1.44269504088896340736f

#define NBLK_H 256     // blocks in hist/scatter passes
#define NBKT_MAX 3136  // >= ceil(N/32)

typedef __attribute__((ext_vector_type(8))) short short8v;   // 8 bf16
typedef __attribute__((ext_vector_type(4))) float f32x4;

__device__ inline short bfs(float v) {
    __hip_bfloat16 b = __float2bfloat16(v);
    return *(short*)&b;
}

__device__ inline int ld_edge(const void* ei, long idx, int is64) {
    return is64 ? (int)((const long long*)ei)[idx] : ((const int*)ei)[idx];
}

// ---------- W1 -> bf16 slices (pre-swizzled) + edge dtype detect ----------
__global__ void k_prepW(const float* __restrict__ W1, ushort* __restrict__ W1b2,
                        const int* __restrict__ ei, int* __restrict__ flag) {
    if (blockIdx.x == 0 && threadIdx.x == 0) {
        int z = 0;
        for (int i = 1; i < 16; i += 2) z += (ei[i] == 0) ? 1 : 0;
        *flag = (z == 8) ? 1 : 0;
    }
    int i = blockIdx.x * 256 + threadIdx.x;
    if (i >= 16 * 64 * 32) return;
    int ks = i >> 11;
    int c = (i >> 5) & 63;
    int st = i & 31;
    int q = (st >> 3) ^ ((c >> 1) & 3);
    int k = ks * 32 + q * 8 + (st & 7);
    float v = (k < F_IN) ? W1[k * HD + c] : 0.f;
    __hip_bfloat16 b = __float2bfloat16(v);
    W1b2[i] = *(ushort*)&b;
}

// ---------- fatA: gemm1 (blocks < gB) || edge histogram (last NBLK_H) ----------
__device__ __forceinline__ void g1_stage(const float* __restrict__ x,
        const ushort* __restrict__ W1b2, char* smem, int buf, int ks,
        int rowb, int N, int lane, int w) {
    const int k0 = ks * 32;
    {
        const ushort* srcB = W1b2 + ks * 2048 + (w * 64 + lane) * 8;
        char* dstB = smem + 16384 + buf * 4096 + w * 1024;
        __builtin_amdgcn_global_load_lds(
            (const __attribute__((address_space(1))) void*)srcB,
            (__attribute__((address_space(3))) void*)dstB, 16, 0, 0);
    }
#pragma unroll
    for (int i = 0; i < 2; ++i) {
        int vt = i * 256 + w * 64 + lane;
        int row = vt >> 3;
        int c = (vt & 7) ^ (row & 7);
        int ke = k0 + c * 4; if (ke > 496) ke = 496;
        int rowg = rowb + row; if (rowg >= N) rowg = N - 1;
        const float* srcA = x + (long)rowg * F_IN + ke;
        char* dstA = smem + buf * 8192 + i * 4096 + w * 1024;
        __builtin_amdgcn_global_load_lds(
            (const __attribute__((address_space(1))) void*)srcA,
            (__attribute__((address_space(3))) void*)dstA, 16, 0, 0);
    }
}

__global__ __launch_bounds__(256) void k_fatA(const float* __restrict__ x,
        const ushort* __restrict__ W1b2,
        const float* __restrict__ asrc, const float* __restrict__ adst,
        float* __restrict__ als, float* __restrict__ ald,
        ushort* __restrict__ h1b, int N,
        const void* ei, int E, int nbkt, int* __restrict__ ghist,
        const int* __restrict__ flag) {
    __shared__ char smem[24576];
    int gB = (N + 63) >> 6;
    int t = threadIdx.x;

    if ((int)blockIdx.x >= gB) {
        // ================= histogram branch =================
        int hb = blockIdx.x - gB;
        int* h = (int*)smem;
        int tot = E + N;
        int epb = (tot + NBLK_H - 1) / NBLK_H;
        int e0 = hb * epb, e1 = min(tot, e0 + epb);
        for (int i = t; i < nbkt; i += 256) h[i] = 0;
        __syncthreads();
        int is64 = *flag;
        for (int e = e0 + t; e < e1; e += 256) {
            int dst = (e < E) ? ld_edge(ei, (long)E + e, is64) : (e - E);
            atomicAdd(&h[dst >> 5], 1);
        }
        __syncthreads();
        for (int i = t; i < nbkt; i += 256)
            ghist[hb * nbkt + i] = h[i];
        return;
    }

    // ================= gemm1 branch =================
    int lane = t & 63;
    int w = t >> 6;
    int l16 = lane & 15, oct = lane >> 4;
    int rowb = blockIdx.x * 64;

    f32x4 acc0 = {0.f, 0.f, 0.f, 0.f};
    f32x4 acc1 = {0.f, 0.f, 0.f, 0.f};
    f32x4 acc2 = {0.f, 0.f, 0.f, 0.f};
    f32x4 acc3 = {0.f, 0.f, 0.f, 0.f};

    g1_stage(x, W1b2, smem, 0, 0, rowb, N, lane, w);
    __syncthreads();

    int rl = w * 16 + l16;
    int asw = l16 & 7;
    int bsw = (l16 >> 1) & 3;

    for (int ks = 0; ks < 16; ++ks) {
        int cur = ks & 1;
        if (ks < 15)
            g1_stage(x, W1b2, smem, cur ^ 1, ks + 1, rowb, N, lane, w);
        const char* Ab = smem + cur * 8192;
        const char* Bb = smem + 16384 + cur * 4096;
        float4 x0 = *reinterpret_cast<const float4*>(
            Ab + rl * 128 + ((2 * oct + 0) ^ asw) * 16);
        float4 x1 = *reinterpret_cast<const float4*>(
            Ab + rl * 128 + ((2 * oct + 1) ^ asw) * 16);
        short8v a;
        a[0] = bfs(x0.x); a[1] = bfs(x0.y); a[2] = bfs(x0.z); a[3] = bfs(x0.w);
        a[4] = bfs(x1.x); a[5] = bfs(x1.y); a[6] = bfs(x1.z); a[7] = bfs(x1.w);
        short8v b0 = *reinterpret_cast<const short8v*>(
            Bb + (0 * 16 + l16) * 64 + (oct ^ bsw) * 16);
        short8v b1 = *reinterpret_cast<const short8v*>(
            Bb + (1 * 16 + l16) * 64 + (oct ^ bsw) * 16);
        short8v b2 = *reinterpret_cast<const short8v*>(
            Bb + (2 * 16 + l16) * 64 + (oct ^ bsw) * 16);
        short8v b3 = *reinterpret_cast<const short8v*>(
            Bb + (3 * 16 + l16) * 64 + (oct ^ bsw) * 16);
        acc0 = __builtin_amdgcn_mfma_f32_16x16x32_bf16(a, b0, acc0, 0, 0, 0);
        acc1 = __builtin_amdgcn_mfma_f32_16x16x32_bf16(a, b1, acc1, 0, 0, 0);
        acc2 = __builtin_amdgcn_mfma_f32_16x16x32_bf16(a, b2, acc2, 0, 0, 0);
        acc3 = __builtin_amdgcn_mfma_f32_16x16x32_bf16(a, b3, acc3, 0, 0, 0);
        __syncthreads();
    }

    float* fs = (float*)smem;   // 64 x 64 f32 = 16 KB
#pragma unroll
    for (int r = 0; r < 4; ++r) {
        int rl_ = w * 16 + oct * 4 + r;
        fs[rl_ * 64 + l16 +  0] = acc0[r];
        fs[rl_ * 64 + l16 + 16] = acc1[r];
        fs[rl_ * 64 + l16 + 32] = acc2[r];
        fs[rl_ * 64 + l16 + 48] = acc3[r];
    }
    __syncthreads();
#pragma unroll
    for (int j = t; j < 512; j += 256) {
        int row = j >> 3, h = j & 7;
        int gn = rowb + row;
        if (gn < N) {
            const float* hp = fs + row * 64 + h * 8;
            float4 v0 = *reinterpret_cast<const float4*>(hp);
            float4 v1 = *reinterpret_cast<const float4*>(hp + 4);
            const float* s = asrc + h * 8;
            const float* d = adst + h * 8;
            float s1 = v0.x * s[0] + v0.y * s[1] + v0.z * s[2] + v0.w * s[3]
                     + v1.x * s[4] + v1.y * s[5] + v1.z * s[6] + v1.w * s[7];
            float s2 = v0.x * d[0] + v0.y * d[1] + v0.z * d[2] + v0.w * d[3]
                     + v1.x * d[4] + v1.y * d[5] + v1.z * d[6] + v1.w * d[7];
            als[gn * 8 + h] = s1 * LOG2E;
            ald[gn * 8 + h] = s2 * LOG2E;
            ushort hb[8];
            hb[0] = (ushort)bfs(v0.x); hb[1] = (ushort)bfs(v0.y);
            hb[2] = (ushort)bfs(v0.z); hb[3] = (ushort)bfs(v0.w);
            hb[4] = (ushort)bfs(v1.x); hb[5] = (ushort)bfs(v1.y);
            hb[6] = (ushort)bfs(v1.z); hb[7] = (ushort)bfs(v1.w);
            *reinterpret_cast<uint4*>(h1b + (long)gn * HD + h * 8) =
                *reinterpret_cast<const uint4*>(hb);
        }
    }
}

// ================= CSR build tail =================

__global__ void k_bsum(const int* __restrict__ ghist, int* __restrict__ colsum, int nbkt) {
    int b = blockIdx.x * 256 + threadIdx.x;
    if (b >= nbkt) return;
    int s = 0;
    for (int i = 0; i < NBLK_H; i++) s += ghist[i * nbkt + b];
    colsum[b] = s;
}

__global__ __launch_bounds__(256) void k_bscan2(const int* __restrict__ colsum,
        int* __restrict__ boff, int nbkt) {
    __shared__ int part[256];
    int per = (nbkt + 255) / 256;
    int t = threadIdx.x;
    int lo = t * per, hi = min(nbkt, lo + per);
    int s = 0;
    for (int i = lo; i < hi; i++) s += colsum[i];
    part[t] = s;
    __syncthreads();
    for (int off = 1; off < 256; off <<= 1) {
        int v = (t >= off) ? part[t - off] : 0;
        __syncthreads();
        part[t] += v;
        __syncthreads();
    }
    int run = (t > 0) ? part[t - 1] : 0;
    for (int i = lo; i < hi; i++) { boff[i] = run; run += colsum[i]; }
    if (t == 255) boff[nbkt] = part[255];
}

__global__ void k_bapply(int* __restrict__ ghist, const int* __restrict__ boff, int nbkt) {
    int b = blockIdx.x * 256 + threadIdx.x;
    if (b >= nbkt) return;
    int run = boff[b];
    for (int i = 0; i < NBLK_H; i++) {
        int v = ghist[i * nbkt + b];
        ghist[i * nbkt + b] = run;
        run += v;
    }
}

__global__ __launch_bounds__(256) void k_scatter(const void* ei, int E, int N, int nbkt,
        const int* __restrict__ ghist, uint* __restrict__ pairs, const int* flag) {
    __shared__ int cur[NBKT_MAX];
    int tot = E + N;
    int epb = (tot + NBLK_H - 1) / NBLK_H;
    int e0 = blockIdx.x * epb, e1 = min(tot, e0 + epb);
    for (int i = threadIdx.x; i < nbkt; i += 256) cur[i] = ghist[blockIdx.x * nbkt + i];
    __syncthreads();
    int is64 = *flag;
    for (int e = e0 + threadIdx.x; e < e1; e += 256) {
        int src, dst;
        if (e < E) { src = ld_edge(ei, e, is64); dst = ld_edge(ei, (long)E + e, is64); }
        else { src = dst = e - E; }
        int pos = atomicAdd(&cur[dst >> 5], 1);
        pairs[pos] = ((uint)src << 5) | (uint)(dst & 31);
    }
}

// ---------- fused deg + scan + fill: one block per 32-node bucket ----------
__global__ __launch_bounds__(256) void k_fill3(const uint* __restrict__ pairs,
        const int* __restrict__ boff, int* __restrict__ rowptr,
        int* __restrict__ csr, int N, int nbkt) {
    __shared__ int cnt[32];
    __shared__ int base[32];
    __shared__ int cur[32];
    int b = blockIdx.x;
    int t = threadIdx.x;
    if (t < 32) { cnt[t] = 0; cur[t] = 0; }
    __syncthreads();
    int p0 = boff[b], p1 = boff[b + 1];
    for (int p = p0 + t; p < p1; p += 256)
        atomicAdd(&cnt[pairs[p] & 31], 1);
    __syncthreads();
    if (t < 32) {
        int pre = 0;
#pragma unroll
        for (int i = 0; i < 32; i++) pre += (i < t) ? cnt[i] : 0;
        base[t] = p0 + pre;
        int n = b * 32 + t;
        if (n < N) rowptr[n] = base[t];
    }
    if (b == 0 && t == 0) rowptr[N] = boff[nbkt];
    __syncthreads();
    for (int p = p0 + t; p < p1; p += 256) {
        uint v = pairs[p];
        int lo = v & 31;
        int pos = base[lo] + atomicAdd(&cur[lo], 1);
        csr[pos] = (int)(v >> 5);
    }
}

// ---------- Layer-1 aggregation + fused layer-2 projection ----------
// 2 nodes per wave (32-lane halves): es = 4 edge slots, h = 8 heads; each
// lane outputs dims d=8h+es and d+4.
__global__ __launch_bounds__(256) void k_agg1(const int* __restrict__ rowptr,
        const int* __restrict__ csr, const ushort* __restrict__ h1b,
        const float* __restrict__ als, const float* __restrict__ ald,
        const float* __restrict__ b1, const float* __restrict__ W2,
        const float* __restrict__ as2, const float* __restrict__ ad2,
        float* __restrict__ h2p, float* __restrict__ ald2, int N) {
    int lane = threadIdx.x & 63;
    int wid = threadIdx.x >> 6;
    int half = lane >> 5;
    int n = blockIdx.x * 8 + wid * 2 + half;
    bool act = (n < N);
    int nc = act ? n : (N - 1);
    int es = (lane >> 3) & 3;
    int h = lane & 7;
    float aldh = ald[nc * HEADS + h];
    int rs = rowptr[nc], re = rowptr[nc + 1];

    float acc[4][8];
    float den[4] = {0.f, 0.f, 0.f, 0.f};
#pragma unroll
    for (int q = 0; q < 4; ++q)
#pragma unroll
        for (int j = 0; j < 8; ++j) acc[q][j] = 0.f;

    int jb = rs;
    for (; jb + 16 <= re; jb += 16) {            // 4 chains in flight
        int s[4]; float e[4]; float p[4]; uint4 u[4];
#pragma unroll
        for (int q = 0; q < 4; ++q) s[q] = csr[jb + q * 4 + es];
#pragma unroll
        for (int q = 0; q < 4; ++q) {
            e[q] = als[s[q] * HEADS + h] + aldh;
            u[q] = *reinterpret_cast<const uint4*>(h1b + (long)s[q] * HD + h * 8);
        }
#pragma unroll
        for (int q = 0; q < 4; ++q) {
            e[q] = fmaxf(e[q], NEG * e[q]);
            p[q] = exp2f(e[q]);
        }
#pragma unroll
        for (int q = 0; q < 4; ++q) {
            acc[q][0] += p[q] * __uint_as_float(u[q].x << 16);
            acc[q][1] += p[q] * __uint_as_float(u[q].x & 0xffff0000u);
            acc[q][2] += p[q] * __uint_as_float(u[q].y << 16);
            acc[q][3] += p[q] * __uint_as_float(u[q].y & 0xffff0000u);
            acc[q][4] += p[q] * __uint_as_float(u[q].z << 16);
            acc[q][5] += p[q] * __uint_as_float(u[q].z & 0xffff0000u);
            acc[q][6] += p[q] * __uint_as_float(u[q].w << 16);
            acc[q][7] += p[q] * __uint_as_float(u[q].w & 0xffff0000u);
            den[q] += p[q];
        }
    }
    for (; jb < re; jb += 4) {                   // guarded tail
        int eidx = jb + es;
        bool valid = (eidx < re);
        int s = csr[valid ? eidx : rs];
        float e = als[s * HEADS + h] + aldh;
        e = fmaxf(e, NEG * e);
        float p = valid ? exp2f(e) : 0.f;
        uint4 u = *reinterpret_cast<const uint4*>(h1b + (long)s * HD + h * 8);
        acc[0][0] += p * __uint_as_float(u.x << 16);
        acc[0][1] += p * __uint_as_float(u.x & 0xffff0000u);
        acc[0][2] += p * __uint_as_float(u.y << 16);
        acc[0][3] += p * __uint_as_float(u.y & 0xffff0000u);
        acc[0][4] += p * __uint_as_float(u.z << 16);
        acc[0][5] += p * __uint_as_float(u.z & 0xffff0000u);
        acc[0][6] += p * __uint_as_float(u.w << 16);
        acc[0][7] += p * __uint_as_float(u.w & 0xffff0000u);
        den[0] += p;
    }
    float a0 = (acc[0][0] + acc[1][0]) + (acc[2][0] + acc[3][0]);
    float a1 = (acc[0][1] + acc[1][1]) + (acc[2][1] + acc[3][1]);
    float a2 = (acc[0][2] + acc[1][2]) + (acc[2][2] + acc[3][2]);
    float a3 = (acc[0][3] + acc[1][3]) + (acc[2][3] + acc[3][3]);
    float a4 = (acc[0][4] + acc[1][4]) + (acc[2][4] + acc[3][4]);
    float a5 = (acc[0][5] + acc[1][5]) + (acc[2][5] + acc[3][5]);
    float a6 = (acc[0][6] + acc[1][6]) + (acc[2][6] + acc[3][6]);
    float a7 = (acc[0][7] + acc[1][7]) + (acc[2][7] + acc[3][7]);
    float dn = (den[0] + den[1]) + (den[2] + den[3]);
#pragma unroll
    for (int off = 8; off <= 16; off <<= 1) {
        dn += __shfl_xor(dn, off);
        a0 += __shfl_xor(a0, off); a1 += __shfl_xor(a1, off);
        a2 += __shfl_xor(a2, off); a3 += __shfl_xor(a3, off);
        a4 += __shfl_xor(a4, off); a5 += __shfl_xor(a5, off);
        a6 += __shfl_xor(a6, off); a7 += __shfl_xor(a7, off);
    }
    float sel_a = (es < 2) ? ((es == 0) ? a0 : a1) : ((es == 2) ? a2 : a3);
    float sel_b = (es < 2) ? ((es == 0) ? a4 : a5) : ((es == 2) ? a6 : a7);
    int da = h * 8 + es, db = da + 4;
    float inv = 1.f / (dn + EPSV);
    float oa = sel_a * inv + b1[da];
    float ob = sel_b * inv + b1[db];
    oa = (oa > 0.f) ? oa : __expf(oa) - 1.f;
    ob = (ob > 0.f) ? ob : __expf(ob) - 1.f;
    float p0 = oa * W2[da * CLS + 0] + ob * W2[db * CLS + 0];
    float p1 = oa * W2[da * CLS + 1] + ob * W2[db * CLS + 1];
    float p2 = oa * W2[da * CLS + 2] + ob * W2[db * CLS + 2];
#pragma unroll
    for (int off = 1; off <= 16; off <<= 1) {
        p0 += __shfl_xor(p0, off);
        p1 += __shfl_xor(p1, off);
        p2 += __shfl_xor(p2, off);
    }
    if ((lane & 31) == 0 && act) {
        float als2v = (p0 * as2[0] + p1 * as2[1] + p2 * as2[2]) * LOG2E;
        *reinterpret_cast<float4*>(h2p + (long)n * 4) =
            make_float4(p0, p1, p2, als2v);   // logit packed in .w
        ald2[n] = (p0 * ad2[0] + p1 * ad2[1] + p2 * ad2[2]) * LOG2E;
    }
}

// ---------- Layer-2 pull aggregation: 2 nodes/wave, 1 line per edge ----------
__global__ __launch_bounds__(256) void k_agg2(const int* __restrict__ rowptr,
        const int* __restrict__ csr, const float* __restrict__ h2p,
        const float* __restrict__ ald2v,
        const float* __restrict__ b2, float* __restrict__ out, int N) {
    int n = blockIdx.x * 8 + (threadIdx.x >> 5);
    if (n >= N) return;
    int lane = threadIdx.x & 31;
    float aldv = ald2v[n];
    int rs = rowptr[n], re = rowptr[n + 1];
    float sum = 0.f, a0 = 0.f, a1 = 0.f, a2 = 0.f;
    for (int j = rs + lane; j < re; j += 32) {
        int s = csr[j];
        float4 hv = *reinterpret_cast<const float4*>(h2p + (long)s * 4);
        float e = hv.w + aldv;
        e = fmaxf(e, NEG * e);
        float p = exp2f(e);
        sum += p;
        a0 += p * hv.x;
        a1 += p * hv.y;
        a2 += p * hv.z;
    }
#pragma unroll
    for (int off = 1; off < 32; off <<= 1) {
        sum += __shfl_xor(sum, off);
        a0 += __shfl_xor(a0, off);
        a1 += __shfl_xor(a1, off);
        a2 += __shfl_xor(a2, off);
    }
    if (lane == 0) {
        float d = sum + EPSV;
        float v0 = a0 / d + b2[0], v1 = a1 / d + b2[1], v2 = a2 / d + b2[2];
        float mx = fmaxf(v0, fmaxf(v1, v2));
        float se = __expf(v0 - mx) + __expf(v1 - mx) + __expf(v2 - mx);
        float ls = mx + __logf(se);
        out[n * CLS + 0] = v0; out[n * CLS + 1] = v1; out[n * CLS + 2] = v2;
        long o2 = (long)N * CLS;
        out[o2 + n * CLS + 0] = v0 - ls;
        out[o2 + n * CLS + 1] = v1 - ls;
        out[o2 + n * CLS + 2] = v2 - ls;
    }
}

extern "C" void kernel_launch(void* const* d_in, const int* in_sizes, int n_in,
                              void* d_out, int out_size, void* d_ws, size_t ws_size,
                              hipStream_t stream) {
    const float* x   = (const float*)d_in[0];
    const void*  ei  = d_in[1];
    const float* W1  = (const float*)d_in[2];
    const float* as1 = (const float*)d_in[3];
    const float* ad1 = (const float*)d_in[4];
    const float* b1  = (const float*)d_in[5];
    const float* W2  = (const float*)d_in[6];
    const float* as2 = (const float*)d_in[7];
    const float* ad2 = (const float*)d_in[8];
    const float* b2  = (const float*)d_in[9];
    int N = in_sizes[0] / F_IN;
    int E = in_sizes[1] / 2;
    int tot = E + N;
    int nbkt = (N + 31) >> 5;

    char* w = (char*)d_ws;
    auto alloc = [&](size_t bytes) -> char* {
        char* p = w; w += (bytes + 255) & ~size_t(255); return p;
    };
    ushort* h1b    = (ushort*)alloc((size_t)N * HD * 2);
    float*  als1   = (float*)alloc((size_t)N * HEADS * 4);
    float*  ald1   = (float*)alloc((size_t)N * HEADS * 4);
    int*    rowptr = (int*)alloc((size_t)(N + 1) * 4);
    int*    csr    = (int*)alloc((size_t)tot * 4);
    float*  h2p    = (float*)alloc((size_t)N * 4 * 4);
    float*  ald2   = (float*)alloc((size_t)N * 4);
    ushort* W1b2   = (ushort*)alloc((size_t)16 * 64 * 32 * 2);
    int*    flag   = (int*)alloc(256);
    uint*   pairs  = (uint*)alloc((size_t)tot * 4);
    int*    ghist  = (int*)alloc((size_t)NBLK_H * nbkt * 4);
    int*    colsum = (int*)alloc((size_t)nbkt * 4);
    int*    boff   = (int*)alloc((size_t)(nbkt + 1) * 4);

    int gB = (N + 63) / 64;
    k_prepW<<<(16 * 64 * 32 + 255) / 256, 256, 0, stream>>>(W1, W1b2, (const int*)ei, flag);
    k_fatA<<<gB + NBLK_H, 256, 0, stream>>>(x, W1b2, as1, ad1, als1, ald1, h1b, N,
                                            ei, E, nbkt, ghist, flag);
    k_bsum<<<(nbkt + 255) / 256, 256, 0, stream>>>(ghist, colsum, nbkt);
    k_bscan2<<<1, 256, 0, stream>>>(colsum, boff, nbkt);
    k_bapply<<<(nbkt + 255) / 256, 256, 0, stream>>>(ghist, boff, nbkt);
    k_scatter<<<NBLK_H, 256, 0, stream>>>(ei, E, N, nbkt, ghist, pairs, flag);
    k_fill3<<<nbkt, 256, 0, stream>>>(pairs, boff, rowptr, csr, N, nbkt);
    k_agg1<<<(N + 7) / 8, 256, 0, stream>>>(rowptr, csr, h1b, als1, ald1, b1,
                                            W2, as2, ad2, h2p, ald2, N);
    k_agg2<<<(N + 7) / 8, 256, 0, stream>>>(rowptr, csr, h2p, ald2, b2,
                                            (float*)d_out, N);
}